// Round 5
// baseline (198.699 us; speedup 1.0000x reference)
//
#include <hip/hip_runtime.h>
#include <math.h>

// ---------------------------------------------------------------------------
// MS-SSIM + MSE loss, (16,3,512,512) f32, 5 pyramid levels.
// R5: column-streaming. Thread owns one output column of a 256-wide strip,
// streams 42 input rows through a 3-row LDS ring (static offsets).
// H-conv (77 fma) feeds a transposed-FIR V-pass held in 55 shift registers
// (55 fma) -> SSIM/CS emit. MSE (L0) + 2x2 avgpool fused on streamed rows.
// No hf LDS array, no runtime LDS addressing. Final kernel reduces in f64.
// ---------------------------------------------------------------------------

#define NPLANES 48

struct GaussW { float g[11]; };

// ws float offsets: pyramids unchanged; partial areas resized (fewer blocks)
#define PYR2_OFF  4177920
#define P_L0      8355840   // 1536 pairs
#define P_L1      8358912   // 384 pairs
#define P_L2      8359680   // 96 pairs
#define P_L3      8359872   // 24 pairs
#define P_L4      8359920   // 6 pairs
#define P_MSE     8359932   // 1536 singles

#define C1F 1.0e-4f
#define C2F 9.0e-4f

// ---------------------------------------------------------------------------
template <int LOGW, int DO_MSE, int DO_POOL>
__global__ __launch_bounds__(256, 4) void ssim_stream(
    const float* __restrict__ x1, const float* __restrict__ x2, GaussW gw,
    float* __restrict__ partials, float* __restrict__ msep,
    float* __restrict__ d1, float* __restrict__ d2)
{
  constexpr int W = 1 << LOGW;
  constexpr int Ho = W - 10;
  constexpr int LOGWB = (LOGW > 8) ? 8 : LOGW;
  constexpr int WB = 1 << LOGWB;     // columns per block (per plane)
  constexpr int P = 256 >> LOGWB;    // planes per block
  constexpr int STRIDE = WB + 12;
  constexpr int W2 = W >> 1;

  __shared__ float rowbuf[3][2 * P][STRIDE];
  __shared__ float red[3][4];

  const int tid = threadIdx.x;
  const int p = tid >> LOGWB;
  const int col = tid & (WB - 1);
  const int bx = blockIdx.x, by = blockIdx.y, bz = blockIdx.z;
  const int gcol = bx * WB + col;            // plane-local column
  const int plane = bz * P + p;
  const size_t pb = (size_t)plane * W * W;
  const float* q1 = x1 + pb + gcol;
  const float* q2 = x2 + pb + gcol;
  const int gr0 = 32 * by;
  const int ROWS = min(42, Ho - gr0 + 10);   // h rows needed by this strip
  const bool xtra = (bx * WB + WB + col) < W;  // extra halo col exists

  // transposed-FIR accumulators: acc*[10] emits out row (rr-10)
  float acc0[11], acc1[11], acc2[11], acc3[11], acc4[11];
#pragma unroll
  for (int j = 0; j < 11; ++j) {
    acc0[j] = 0.f; acc1[j] = 0.f; acc2[j] = 0.f; acc3[j] = 0.f; acc4[j] = 0.f;
  }

  float mse_acc = 0.f, ssim_acc = 0.f, cs_acc = 0.f;

  // ---- prologue: row 0 into slot 0 ----
  {
    size_t ro = (size_t)gr0 * W;
    float a = q1[ro], b = q2[ro];
    float ae = 0.f, be = 0.f;
    if (col < 12 && xtra) { ae = q1[ro + WB]; be = q2[ro + WB]; }
    if (DO_MSE) { float d = a - b; mse_acc = d * d; }
    rowbuf[0][2 * p][col] = a;
    rowbuf[0][2 * p + 1][col] = b;
    if (col < 12) {
      rowbuf[0][2 * p][WB + col] = ae;
      rowbuf[0][2 * p + 1][WB + col] = be;
    }
  }
  __syncthreads();

  int cur = 0;
  for (int rr = 0; rr < ROWS; ++rr) {
    int nxt = cur + 1; if (nxt == 3) nxt = 0;
    int prv = cur - 1; if (prv < 0) prv = 2;
    const bool have = (rr + 1) < ROWS;  // uniform

    // issue next row's global loads early (hide HBM under compute)
    float a = 0.f, b = 0.f, ae = 0.f, be = 0.f;
    if (have) {
      size_t ro = (size_t)(gr0 + rr + 1) * W;
      a = q1[ro]; b = q2[ro];
      if (col < 12 && xtra) { ae = q1[ro + WB]; be = q2[ro + WB]; }
    }

    // ---- H-pass: 11-tap window from rowbuf[cur], static offsets ----
    const float* r1 = &rowbuf[cur][2 * p][col];
    const float* r2 = &rowbuf[cur][2 * p + 1][col];
    float s1 = 0.f, s2 = 0.f, s11 = 0.f, s22 = 0.f, s12 = 0.f;
#pragma unroll
    for (int k = 0; k < 11; ++k) {
      float av = r1[k], bv = r2[k], w = gw.g[k];
      float wa = w * av, wb = w * bv;
      s1 += wa; s2 += wb;
      s11 = fmaf(wa, av, s11);
      s22 = fmaf(wb, bv, s22);
      s12 = fmaf(wa, bv, s12);
    }

    // ---- V-pass: shift-accumulate (all indices static) ----
#pragma unroll
    for (int j = 10; j >= 1; --j) {
      acc0[j] = fmaf(gw.g[j], s1, acc0[j - 1]);
      acc1[j] = fmaf(gw.g[j], s2, acc1[j - 1]);
      acc2[j] = fmaf(gw.g[j], s11, acc2[j - 1]);
      acc3[j] = fmaf(gw.g[j], s22, acc3[j - 1]);
      acc4[j] = fmaf(gw.g[j], s12, acc4[j - 1]);
    }
    acc0[0] = gw.g[0] * s1;
    acc1[0] = gw.g[0] * s2;
    acc2[0] = gw.g[0] * s11;
    acc3[0] = gw.g[0] * s22;
    acc4[0] = gw.g[0] * s12;

    // ---- emit SSIM/CS for out row rr-10 (row bound guaranteed by ROWS) ----
    if (rr >= 10 && gcol < Ho) {
      float m1 = acc0[10], m2 = acc1[10];
      float m1sq = m1 * m1, m2sq = m2 * m2, m12 = m1 * m2;
      float v1 = 2.f * (acc4[10] - m12) + C2F;
      float v2 = (acc2[10] - m1sq) + (acc3[10] - m2sq) + C2F;
      float csv = v1 * __builtin_amdgcn_rcpf(v2);
      cs_acc += csv;
      ssim_acc += csv * (2.f * m12 + C1F) *
                  __builtin_amdgcn_rcpf(m1sq + m2sq + C1F);
    }

    // ---- fused 2x2 avgpool on raw row pair (prv, cur) ----
    if (DO_POOL && (rr & 1) && rr < 32 && col < (WB / 2)) {
      float a00 = rowbuf[prv][2 * p][2 * col], a01 = rowbuf[prv][2 * p][2 * col + 1];
      float a10 = rowbuf[cur][2 * p][2 * col], a11 = rowbuf[cur][2 * p][2 * col + 1];
      float b00 = rowbuf[prv][2 * p + 1][2 * col], b01 = rowbuf[prv][2 * p + 1][2 * col + 1];
      float b10 = rowbuf[cur][2 * p + 1][2 * col], b11 = rowbuf[cur][2 * p + 1][2 * col + 1];
      int orow = 16 * by + (rr >> 1);
      size_t ob = (size_t)plane * W2 * W2 + (size_t)orow * W2 + bx * (WB / 2) + col;
      d1[ob] = 0.25f * ((a00 + a01) + (a10 + a11));
      d2[ob] = 0.25f * ((b00 + b01) + (b10 + b11));
    }

    // ---- stage next row into slot nxt ----
    if (have) {
      if (DO_MSE && (rr + 1) < 32) { float d = a - b; mse_acc = fmaf(d, d, mse_acc); }
      rowbuf[nxt][2 * p][col] = a;
      rowbuf[nxt][2 * p + 1][col] = b;
      if (col < 12) {
        rowbuf[nxt][2 * p][WB + col] = ae;
        rowbuf[nxt][2 * p + 1][WB + col] = be;
      }
      __syncthreads();
    }
    cur = nxt;
  }

  // ---- block reduce (ssim, cs, mse) ----
#pragma unroll
  for (int off = 32; off; off >>= 1) {
    ssim_acc += __shfl_down(ssim_acc, off);
    cs_acc += __shfl_down(cs_acc, off);
    if (DO_MSE) mse_acc += __shfl_down(mse_acc, off);
  }
  int wave = tid >> 6, lane = tid & 63;
  if (lane == 0) {
    red[0][wave] = ssim_acc;
    red[1][wave] = cs_acc;
    if (DO_MSE) red[2][wave] = mse_acc;
  }
  __syncthreads();
  if (tid == 0) {
    float s = 0.f, cc = 0.f, m = 0.f;
#pragma unroll
    for (int i = 0; i < 4; ++i) {
      s += red[0][i];
      cc += red[1][i];
      if (DO_MSE) m += red[2][i];
    }
    int bi = (bz * gridDim.y + by) * gridDim.x + bx;
    partials[2 * bi] = s;
    partials[2 * bi + 1] = cc;
    if (DO_MSE) msep[bi] = m;
  }
}

// ---------------------------------------------------------------------------
__global__ __launch_bounds__(256) void final_kernel(
    const float* __restrict__ ws, float* __restrict__ out)
{
  __shared__ double sred[2][4];
  __shared__ double fin[11];  // ssim[5], cs[5], mse
  const int tid = threadIdx.x;
  const int offs[5] = {P_L0, P_L1, P_L2, P_L3, P_L4};
  const int cnts[5] = {1536, 384, 96, 24, 6};

  for (int l = 0; l < 5; ++l) {
    double s0 = 0.0, s1 = 0.0;
    for (int i = tid; i < cnts[l]; i += 256) {
      s0 += (double)ws[offs[l] + 2 * i];
      s1 += (double)ws[offs[l] + 2 * i + 1];
    }
#pragma unroll
    for (int off = 32; off; off >>= 1) {
      s0 += __shfl_down(s0, off);
      s1 += __shfl_down(s1, off);
    }
    if ((tid & 63) == 0) { sred[0][tid >> 6] = s0; sred[1][tid >> 6] = s1; }
    __syncthreads();
    if (tid == 0) {
      double aa = 0.0, bb = 0.0;
      for (int i = 0; i < 4; ++i) { aa += sred[0][i]; bb += sred[1][i]; }
      fin[l] = aa;
      fin[5 + l] = bb;
    }
    __syncthreads();
  }

  {
    double s0 = 0.0;
    for (int i = tid; i < 1536; i += 256) s0 += (double)ws[P_MSE + i];
#pragma unroll
    for (int off = 32; off; off >>= 1) s0 += __shfl_down(s0, off);
    if ((tid & 63) == 0) sred[0][tid >> 6] = s0;
    __syncthreads();
    if (tid == 0) {
      double aa = 0.0;
      for (int i = 0; i < 4; ++i) aa += sred[0][i];
      fin[10] = aa;
    }
    __syncthreads();
  }

  if (tid == 0) {
    const double wts[5] = {0.0448, 0.2856, 0.3001, 0.2363, 0.1333};
    const double dims[5] = {502.0, 246.0, 118.0, 54.0, 22.0};
    double mssim[5], mcs[5];
    for (int l = 0; l < 5; ++l) {
      double n = 48.0 * dims[l] * dims[l];
      mssim[l] = fin[l] / n;
      mcs[l] = fin[5 + l] / n;
    }
    // literal pytorch_msssim translation: prod(pow1[:-1] * pow2[-1])
    double p2last = pow(mssim[4], wts[4]);
    double prod = 1.0;
    for (int i = 0; i < 4; ++i) prod *= pow(mcs[i], wts[i]) * p2last;
    double msssim = prod;
    double mse = fin[10] / 12582912.0;
    out[0] = (float)(mse - msssim + 1.0);
    out[1] = (float)msssim;
  }
}

// ---------------------------------------------------------------------------
extern "C" void kernel_launch(void* const* d_in, const int* in_sizes, int n_in,
                              void* d_out, int out_size, void* d_ws, size_t ws_size,
                              hipStream_t stream)
{
  const float* rec = (const float*)d_in[0];   // reconst
  const float* orig = (const float*)d_in[1];  // original
  float* ws = (float*)d_ws;
  float* out = (float*)d_out;

  GaussW gw;
  {
    double g[11], s = 0.0;
    for (int i = 0; i < 11; ++i) {
      double x = (double)i - 5.0;
      g[i] = exp(-(x * x) / 4.5);
      s += g[i];
    }
    for (int i = 0; i < 11; ++i) gw.g[i] = (float)(g[i] / s);
  }

  // pyramid pointers
  float* A1 = ws + 0;        // img1 L1..L4
  float* A2 = ws + 3145728;
  float* A3 = ws + 3932160;
  float* A4 = ws + 4128768;
  float* B1 = ws + PYR2_OFF;
  float* B2 = ws + PYR2_OFF + 3145728;
  float* B3 = ws + PYR2_OFF + 3932160;
  float* B4 = ws + PYR2_OFF + 4128768;

  ssim_stream<9, 1, 1><<<dim3(2, 16, 48), 256, 0, stream>>>(
      orig, rec, gw, ws + P_L0, ws + P_MSE, A1, B1);
  ssim_stream<8, 0, 1><<<dim3(1, 8, 48), 256, 0, stream>>>(
      A1, B1, gw, ws + P_L1, nullptr, A2, B2);
  ssim_stream<7, 0, 1><<<dim3(1, 4, 24), 256, 0, stream>>>(
      A2, B2, gw, ws + P_L2, nullptr, A3, B3);
  ssim_stream<6, 0, 1><<<dim3(1, 2, 12), 256, 0, stream>>>(
      A3, B3, gw, ws + P_L3, nullptr, A4, B4);
  ssim_stream<5, 0, 0><<<dim3(1, 1, 6), 256, 0, stream>>>(
      A4, B4, gw, ws + P_L4, nullptr, nullptr, nullptr);

  final_kernel<<<dim3(1), dim3(256), 0, stream>>>(ws, out);
}